// Round 1
// baseline (636.258 us; speedup 1.0000x reference)
//
#include <hip/hip_runtime.h>
#include <cstdint>

#define B_    16
#define L_    512
#define D_    768
#define DFF_  3072
#define DLLM_ 4096
#define E_    8

typedef unsigned short ushort_t;
typedef __attribute__((ext_vector_type(4))) float accfrag_t;
typedef __attribute__((ext_vector_type(8))) short bfrag_t;

typedef __attribute__((address_space(3))) uint32_t lds_u32;
typedef __attribute__((address_space(1))) uint32_t glb_u32;

__device__ inline void gload16(const void* g, void* l) {
  // global -> LDS direct copy, 16B per lane; LDS dest is wave-uniform base + lane*16
  __builtin_amdgcn_global_load_lds((const glb_u32*)(uintptr_t)g,
                                   (lds_u32*)(uint32_t)(uintptr_t)l, 16, 0, 0);
}

__device__ inline ushort_t f2bf(float f) {
  uint32_t u = __float_as_uint(f);
  return (ushort_t)((u + 0x7FFFu + ((u >> 16) & 1u)) >> 16);  // RNE, matches .astype(bf16)
}
__device__ inline float bf2f(ushort_t v) { return __uint_as_float(((uint32_t)v) << 16); }

#define MFMA16(a, b, c) __builtin_amdgcn_mfma_f32_16x16x32_bf16(a, b, c, 0, 0, 0)

// ---------------------------------------------------------------------------
// 128x128 tile GEMM body, BK=64, 4 waves (2x2), double-buffered LDS,
// global_load_lds staging with XOR-swizzled layout (swizzle folded into the
// per-lane GLOBAL source address; LDS dest stays linear).
// A panel: 128 rows x K bf16 row-major, row stride LDB bytes.
// B panel: 128 rows (= output cols) x K bf16 row-major (pre-transposed weights).
// ---------------------------------------------------------------------------
template <int KT, int LDB>
__device__ inline void gemm_body(const char* gA, const char* gB, char* sm,
                                 accfrag_t acc[4][4]) {
  const int tid = threadIdx.x;
  const int lane = tid & 63, w = tid >> 6;
  const int wm = w >> 1, wn = w & 1;
  // staging: inst i covers LDS rows [i*8, i*8+8); lane -> row i*8 + (lane>>3),
  // 16B chunk (lane&7); swizzled source chunk = ((lane&7) ^ (lane>>3))*16
  const int cb = (((lane & 7) ^ (lane >> 3)) << 4);
  const char* sA = gA + (size_t)(lane >> 3) * LDB + cb;
  const char* sB = gB + (size_t)(lane >> 3) * LDB + cb;

  auto STAGE = [&](int bf, int t) {
    char* dst = sm + bf * 32768;
    const size_t ko = (size_t)t * 128;
#pragma unroll
    for (int ii = 0; ii < 4; ++ii) {
      const int i = w * 4 + ii;
      gload16(sA + (size_t)i * 8 * LDB + ko, dst + i * 1024);
      gload16(sB + (size_t)i * 8 * LDB + ko, dst + 16384 + i * 1024);
    }
  };

  int buf = 0;
  STAGE(0, 0);
  __syncthreads();
  for (int t = 0; t < KT; ++t) {
    if (t + 1 < KT) STAGE(buf ^ 1, t + 1);
    const char* Ab = sm + buf * 32768;
    const char* Bb = Ab + 16384;
    bfrag_t af[2][4], bfr[2][4];
#pragma unroll
    for (int kk = 0; kk < 2; ++kk) {
      const int kbyte = ((kk * 64) + ((lane >> 4) << 4)) ^ ((lane & 7) << 4);
#pragma unroll
      for (int m = 0; m < 4; ++m)
        af[kk][m] = *(const bfrag_t*)(Ab + ((wm * 64 + m * 16 + (lane & 15)) << 7) + kbyte);
#pragma unroll
      for (int n = 0; n < 4; ++n)
        bfr[kk][n] = *(const bfrag_t*)(Bb + ((wn * 64 + n * 16 + (lane & 15)) << 7) + kbyte);
    }
#pragma unroll
    for (int m = 0; m < 4; ++m)
#pragma unroll
      for (int n = 0; n < 4; ++n) {
        acc[m][n] = MFMA16(af[0][m], bfr[0][n], acc[m][n]);
        acc[m][n] = MFMA16(af[1][m], bfr[1][n], acc[m][n]);
      }
    __syncthreads();
    buf ^= 1;
  }
}

// ---------------------------------------------------------------------------
// GEMM1: h = GELU_tanh(x @ W1 + b1), output bf16 [JP][512][3072]
// job = b*3 + s; s<2: routed expert tidx[b*2+s]; s==2: general (index 8)
// ---------------------------------------------------------------------------
__global__ __launch_bounds__(256, 2)
void gemm1_k(const ushort_t* __restrict__ xb, const ushort_t* __restrict__ w1t,
             const float* __restrict__ e_b1, const float* __restrict__ g_b1,
             const int* __restrict__ tidx, ushort_t* __restrict__ h_out, int job0) {
  __shared__ char sm[65536];
  const int mt = blockIdx.x & 3, nt = blockIdx.x >> 2;  // 4 x 24 tiles
  const int jp = blockIdx.y, job = job0 + jp;
  const int b = job / 3, s = job - b * 3;
  const int e = (s < 2) ? tidx[b * 2 + s] : E_;
  const char* gA = (const char*)(xb + ((size_t)b * L_ + mt * 128) * D_);
  const char* gB = (const char*)(w1t + ((size_t)e * DFF_ + nt * 128) * D_);
  accfrag_t acc[4][4] = {};
  gemm_body<12, 2 * D_>(gA, gB, sm, acc);

  const float* b1 = (s < 2) ? (e_b1 + (size_t)e * DFF_) : g_b1;
  const int lane = threadIdx.x & 63, w = threadIdx.x >> 6;
  const int wm = w >> 1, wn = w & 1;
#pragma unroll
  for (int m = 0; m < 4; ++m)
#pragma unroll
    for (int n = 0; n < 4; ++n)
#pragma unroll
      for (int r = 0; r < 4; ++r) {
        const int grow = mt * 128 + wm * 64 + m * 16 + ((lane >> 4) << 2) + r;
        const int gcol = nt * 128 + wn * 64 + n * 16 + (lane & 15);
        float v = acc[m][n][r] + b1[gcol];
        float u = 0.7978845608028654f * (v + 0.044715f * v * v * v);
        float th = 1.0f - 2.0f / (1.0f + __expf(2.0f * u));  // tanh(u)
        h_out[((size_t)jp * L_ + grow) * DFF_ + gcol] = f2bf(0.5f * v * (1.0f + th));
      }
}

// ---------------------------------------------------------------------------
// GEMM2: o = h @ W2 + b2 + x (residual). Slots (s<2) -> bf16 slot buffer;
// general (s==2) -> f32 d_out (pre-LN).
// ---------------------------------------------------------------------------
__global__ __launch_bounds__(256, 2)
void gemm2_k(const ushort_t* __restrict__ h_in, const ushort_t* __restrict__ w2t,
             const float* __restrict__ e_b2, const float* __restrict__ g_b2,
             const float* __restrict__ x_f, const int* __restrict__ tidx,
             ushort_t* __restrict__ slot_o, float* __restrict__ outp, int job0) {
  __shared__ char sm[65536];
  const int mt = blockIdx.x & 3, nt = blockIdx.x >> 2;  // 4 x 6 tiles
  const int jp = blockIdx.y, job = job0 + jp;
  const int b = job / 3, s = job - b * 3;
  const int e = (s < 2) ? tidx[b * 2 + s] : E_;
  const char* gA = (const char*)(h_in + ((size_t)jp * L_ + mt * 128) * DFF_);
  const char* gB = (const char*)(w2t + ((size_t)e * D_ + nt * 128) * DFF_);
  accfrag_t acc[4][4] = {};
  gemm_body<48, 2 * DFF_>(gA, gB, sm, acc);

  const float* b2 = (s < 2) ? (e_b2 + (size_t)e * D_) : g_b2;
  const int lane = threadIdx.x & 63, w = threadIdx.x >> 6;
  const int wm = w >> 1, wn = w & 1;
#pragma unroll
  for (int m = 0; m < 4; ++m)
#pragma unroll
    for (int n = 0; n < 4; ++n)
#pragma unroll
      for (int r = 0; r < 4; ++r) {
        const int grow = mt * 128 + wm * 64 + m * 16 + ((lane >> 4) << 2) + r;
        const int gcol = nt * 128 + wn * 64 + n * 16 + (lane & 15);
        float v = acc[m][n][r] + b2[gcol] + x_f[((size_t)b * L_ + grow) * D_ + gcol];
        if (s < 2)
          slot_o[(((size_t)b * 2 + s) * L_ + grow) * D_ + gcol] = f2bf(v);
        else
          outp[((size_t)b * L_ + grow) * D_ + gcol] = v;
      }
}

// ---------------------------------------------------------------------------
// Weight transpose + f32->bf16: src [R][C] f32 (9 matrices: 8 experts + general)
// -> dst [9][C][R] bf16
// ---------------------------------------------------------------------------
__global__ void transpose_cvt_k(const float* __restrict__ srcE, const float* __restrict__ srcG,
                                ushort_t* __restrict__ dst, int R, int C) {
  const int z = blockIdx.z;
  const float* src = (z < 8) ? (srcE + (size_t)z * R * C) : srcG;
  ushort_t* out = dst + (size_t)z * R * C;
  __shared__ float tile[32][33];
  const int c0 = blockIdx.x * 32, r0 = blockIdx.y * 32;
  const int tx = threadIdx.x & 31, ty = threadIdx.x >> 5;
#pragma unroll
  for (int i = 0; i < 32; i += 8)
    tile[ty + i][tx] = src[(size_t)(r0 + ty + i) * C + c0 + tx];
  __syncthreads();
#pragma unroll
  for (int i = 0; i < 32; i += 8)
    out[(size_t)(c0 + ty + i) * R + r0 + tx] = f2bf(tile[tx][ty + i]);
}

__global__ void cvt_x_k(const float* __restrict__ in, ushort_t* __restrict__ out) {
  const int i = (blockIdx.x * 256 + threadIdx.x) * 4;
  const float4 v = *(const float4*)(in + i);
  uint2 u;
  u.x = (uint32_t)f2bf(v.x) | ((uint32_t)f2bf(v.y) << 16);
  u.y = (uint32_t)f2bf(v.z) | ((uint32_t)f2bf(v.w) << 16);
  *(uint2*)(out + i) = u;
}

// ---------------------------------------------------------------------------
// Router: h = relu(emb @ We + cyc*Wc + b), k-split partials for parallelism
// ---------------------------------------------------------------------------
__global__ void router_partial_k(const float* __restrict__ emb, const float* __restrict__ We,
                                 float* __restrict__ rp) {
  const int nt = blockIdx.x, kb = blockIdx.y;  // 24 x 8
  const int t = threadIdx.x, fl = t & 127, bh = t >> 7;
  const int f = nt * 128 + fl;
  float acc[8] = {0, 0, 0, 0, 0, 0, 0, 0};
  const int k0 = kb * 512;
  for (int k = k0; k < k0 + 512; ++k) {
    const float wv = We[(size_t)k * DFF_ + f];
#pragma unroll
    for (int j = 0; j < 8; ++j)
      acc[j] += emb[(size_t)(bh * 8 + j) * DLLM_ + k] * wv;
  }
#pragma unroll
  for (int j = 0; j < 8; ++j)
    rp[(((size_t)nt * 8 + kb) * 16 + bh * 8 + j) * 128 + fl] = acc[j];
}

__global__ void router_reduce_k(const float* __restrict__ rp, const float* __restrict__ cyc,
                                const float* __restrict__ Wc, const float* __restrict__ gb,
                                float* __restrict__ hr) {
  const int g = blockIdx.x * 256 + threadIdx.x;  // 0..49151
  const int b = g / DFF_, f = g - b * DFF_;
  const int nt = f >> 7, fl = f & 127;
  float s = 0.0f;
#pragma unroll
  for (int kb = 0; kb < 8; ++kb)
    s += rp[(((size_t)nt * 8 + kb) * 16 + b) * 128 + fl];
  s += cyc[b] * Wc[f] + gb[f];
  hr[(size_t)b * DFF_ + f] = fmaxf(s, 0.0f);
}

__global__ void router_final_k(const float* __restrict__ hr, const float* __restrict__ Wo,
                               const float* __restrict__ bo, int* __restrict__ tidx,
                               float* __restrict__ gates) {
  const int b = blockIdx.x, tid = threadIdx.x;
  float acc[E_] = {};
  for (int f = tid; f < DFF_; f += 256) {
    const float hv = hr[(size_t)b * DFF_ + f];
#pragma unroll
    for (int o = 0; o < E_; ++o) acc[o] += hv * Wo[(size_t)f * E_ + o];
  }
  __shared__ float lred[E_][4];
#pragma unroll
  for (int o = 0; o < E_; ++o) {
    float v = acc[o];
#pragma unroll
    for (int off = 32; off > 0; off >>= 1) v += __shfl_down(v, off, 64);
    if ((tid & 63) == 0) lred[o][tid >> 6] = v;
  }
  __syncthreads();
  if (tid == 0) {
    float lg[E_];
    float mx = -1e30f;
    for (int o = 0; o < E_; ++o) {
      lg[o] = lred[o][0] + lred[o][1] + lred[o][2] + lred[o][3] + bo[o];
      mx = fmaxf(mx, lg[o]);
    }
    int i1 = 0;
    for (int o = 1; o < E_; ++o) if (lg[o] > lg[i1]) i1 = o;        // ties -> lowest idx
    int i2 = (i1 == 0) ? 1 : 0;
    for (int o = 0; o < E_; ++o) if (o != i1 && lg[o] > lg[i2]) i2 = o;
    float p[E_], sum = 0.0f;
    for (int o = 0; o < E_; ++o) { p[o] = __expf(lg[o] - mx); sum += p[o]; }
    const float p1 = p[i1] / sum, p2 = p[i2] / sum;
    const float den = p1 + p2 + 1e-9f;
    tidx[b * 2] = i1; tidx[b * 2 + 1] = i2;
    gates[b * 2] = p1 / den; gates[b * 2 + 1] = p2 / den;
  }
}

// ---------------------------------------------------------------------------
// Final: 3-way LayerNorm (general in d_out, 2 slots bf16) + gating + bf16 cast
// of combined, out = LN_general + bf16(g0*LN0 + g1*LN1)   (f32 output)
// ---------------------------------------------------------------------------
__global__ __launch_bounds__(256)
void final_ln_k(float* __restrict__ outp, const ushort_t* __restrict__ so,
                const float* __restrict__ gates, const int* __restrict__ tidx,
                const float* __restrict__ e_gam, const float* __restrict__ e_bet,
                const float* __restrict__ g_gam, const float* __restrict__ g_bet) {
  const int row = blockIdx.x;  // b*512 + l
  const int b = row >> 9, l = row & 511;
  const int tid = threadIdx.x;
  __shared__ float red4[4];
  float* gr = outp + (size_t)row * D_;
  const ushort_t* s0 = so + (((size_t)b * 2 + 0) * L_ + l) * D_;
  const ushort_t* s1 = so + (((size_t)b * 2 + 1) * L_ + l) * D_;
  float a0[3], a1[3], a2[3];
#pragma unroll
  for (int j = 0; j < 3; ++j) {
    const int d = tid + j * 256;
    a0[j] = gr[d];
    a1[j] = bf2f(s0[d]);
    a2[j] = bf2f(s1[d]);
  }
  auto bsum = [&](float v) -> float {
#pragma unroll
    for (int o = 32; o > 0; o >>= 1) v += __shfl_down(v, o, 64);
    if ((tid & 63) == 0) red4[tid >> 6] = v;
    __syncthreads();
    const float r = red4[0] + red4[1] + red4[2] + red4[3];
    __syncthreads();
    return r;
  };
  const float sg = bsum(a0[0] + a0[1] + a0[2]);
  const float qg = bsum(a0[0] * a0[0] + a0[1] * a0[1] + a0[2] * a0[2]);
  const float s0s = bsum(a1[0] + a1[1] + a1[2]);
  const float q0s = bsum(a1[0] * a1[0] + a1[1] * a1[1] + a1[2] * a1[2]);
  const float s1s = bsum(a2[0] + a2[1] + a2[2]);
  const float q1s = bsum(a2[0] * a2[0] + a2[1] * a2[1] + a2[2] * a2[2]);
  const float inv = 1.0f / 768.0f;
  const float mug = sg * inv, rg = rsqrtf(qg * inv - mug * mug + 1e-5f);
  const float mu0 = s0s * inv, r0 = rsqrtf(q0s * inv - mu0 * mu0 + 1e-5f);
  const float mu1 = s1s * inv, r1 = rsqrtf(q1s * inv - mu1 * mu1 + 1e-5f);
  const int e0 = tidx[b * 2], e1 = tidx[b * 2 + 1];
  const float g0 = gates[b * 2], g1 = gates[b * 2 + 1];
#pragma unroll
  for (int j = 0; j < 3; ++j) {
    const int d = tid + j * 256;
    const float lng = (a0[j] - mug) * rg * g_gam[d] + g_bet[d];
    const float ln0 = (a1[j] - mu0) * r0 * e_gam[(size_t)e0 * D_ + d] + e_bet[(size_t)e0 * D_ + d];
    const float ln1 = (a2[j] - mu1) * r1 * e_gam[(size_t)e1 * D_ + d] + e_bet[(size_t)e1 * D_ + d];
    const float comb = g0 * ln0 + g1 * ln1;
    gr[d] = lng + bf2f(f2bf(comb));
  }
}

// ---------------------------------------------------------------------------
extern "C" void kernel_launch(void* const* d_in, const int* in_sizes, int n_in,
                              void* d_out, int out_size, void* d_ws, size_t ws_size,
                              hipStream_t stream) {
  const float* x_f  = (const float*)d_in[0];
  const float* cyc  = (const float*)d_in[1];
  const float* emb  = (const float*)d_in[2];
  const float* We   = (const float*)d_in[3];
  const float* Wc   = (const float*)d_in[4];
  const float* gb   = (const float*)d_in[5];
  const float* Wo   = (const float*)d_in[6];
  const float* bo   = (const float*)d_in[7];
  const float* e_w1 = (const float*)d_in[8];
  const float* e_b1 = (const float*)d_in[9];
  const float* e_w2 = (const float*)d_in[10];
  const float* e_b2 = (const float*)d_in[11];
  const float* e_gam = (const float*)d_in[12];
  const float* e_bet = (const float*)d_in[13];
  const float* g_w1 = (const float*)d_in[14];
  const float* g_b1 = (const float*)d_in[15];
  const float* g_w2 = (const float*)d_in[16];
  const float* g_b2 = (const float*)d_in[17];
  const float* g_gam = (const float*)d_in[18];
  const float* g_bet = (const float*)d_in[19];
  float* outp = (float*)d_out;
  char* ws = (char*)d_ws;

  size_t off = 0;
  auto alloc = [&](size_t bytes) { size_t o = off; off = (off + bytes + 255) & ~(size_t)255; return o; };
  const size_t o_idx  = alloc(32 * 4);
  const size_t o_gate = alloc(32 * 4);
  const size_t o_hr   = alloc((size_t)B_ * DFF_ * 4);
  const size_t o_rp   = alloc((size_t)24 * 8 * 16 * 128 * 4);
  const size_t o_xb   = alloc((size_t)B_ * L_ * D_ * 2);
  const size_t o_w1t  = alloc((size_t)9 * DFF_ * D_ * 2);
  const size_t o_w2t  = alloc((size_t)9 * D_ * DFF_ * 2);
  const size_t o_so   = alloc((size_t)B_ * 2 * L_ * D_ * 2);
  const size_t o_h    = off;  // h buffer: JP * 512 * 3072 * 2 bytes

  int JP = 1;
  const int divs[10] = {48, 24, 16, 12, 8, 6, 4, 3, 2, 1};
  for (int k = 0; k < 10; ++k) {
    if (o_h + (size_t)divs[k] * L_ * DFF_ * 2 <= ws_size) { JP = divs[k]; break; }
  }

  ushort_t* xb    = (ushort_t*)(ws + o_xb);
  ushort_t* w1t   = (ushort_t*)(ws + o_w1t);
  ushort_t* w2t   = (ushort_t*)(ws + o_w2t);
  ushort_t* so    = (ushort_t*)(ws + o_so);
  ushort_t* h_ws  = (ushort_t*)(ws + o_h);
  int*      tidx  = (int*)(ws + o_idx);
  float*    gates = (float*)(ws + o_gate);
  float*    hr    = (float*)(ws + o_hr);
  float*    rp    = (float*)(ws + o_rp);

  cvt_x_k<<<dim3((B_ * L_ * D_) / 1024), dim3(256), 0, stream>>>(x_f, xb);
  transpose_cvt_k<<<dim3(96, 24, 9), dim3(256), 0, stream>>>(e_w1, g_w1, w1t, D_, DFF_);
  transpose_cvt_k<<<dim3(24, 96, 9), dim3(256), 0, stream>>>(e_w2, g_w2, w2t, DFF_, D_);
  router_partial_k<<<dim3(24, 8), dim3(256), 0, stream>>>(emb, We, rp);
  router_reduce_k<<<dim3(192), dim3(256), 0, stream>>>(rp, cyc, Wc, gb, hr);
  router_final_k<<<dim3(16), dim3(256), 0, stream>>>(hr, Wo, bo, tidx, gates);

  const int passes = 48 / JP;
  for (int p = 0; p < passes; ++p) {
    gemm1_k<<<dim3(96, JP), dim3(256), 0, stream>>>(xb, w1t, e_b1, g_b1, tidx, h_ws, p * JP);
    gemm2_k<<<dim3(24, JP), dim3(256), 0, stream>>>(h_ws, w2t, e_b2, g_b2, x_f, tidx, so, outp, p * JP);
  }
  final_ln_k<<<dim3(B_ * L_), dim3(256), 0, stream>>>(outp, so, gates, tidx,
                                                      e_gam, e_bet, g_gam, g_bet);
}

// Round 2
// 592.977 us; speedup vs baseline: 1.0730x; 1.0730x over previous
//
#include <hip/hip_runtime.h>
#include <cstdint>

#define B_    16
#define L_    512
#define D_    768
#define DFF_  3072
#define DLLM_ 4096
#define E_    8

typedef unsigned short ushort_t;
typedef __attribute__((ext_vector_type(4))) float accfrag_t;
typedef __attribute__((ext_vector_type(8))) short bfrag_t;

typedef __attribute__((address_space(3))) uint32_t lds_u32;
typedef __attribute__((address_space(1))) uint32_t glb_u32;

__device__ inline void gload16(const void* g, void* l) {
  __builtin_amdgcn_global_load_lds((const glb_u32*)(uintptr_t)g,
                                   (lds_u32*)(uint32_t)(uintptr_t)l, 16, 0, 0);
}

__device__ inline ushort_t f2bf(float f) {
  uint32_t u = __float_as_uint(f);
  return (ushort_t)((u + 0x7FFFu + ((u >> 16) & 1u)) >> 16);  // RNE
}
__device__ inline float bf2f(ushort_t v) { return __uint_as_float(((uint32_t)v) << 16); }

#define MFMA16(a, b, c) __builtin_amdgcn_mfma_f32_16x16x32_bf16(a, b, c, 0, 0, 0)

// ---------------------------------------------------------------------------
// 256x256 tile GEMM, BK=32, 8 waves (2M x 4N), 512 threads.
// 4-deep LDS buffering (4 x 32KB = 128KB), counted vmcnt(8) per K-tile,
// raw s_barrier (no compiler vmcnt(0) drain), setprio around MFMA clusters.
// While computing tile t (buf t&3) we stage tile t+3 (buf (t+3)&3) -- that
// buffer's last readers (tile t-1) finished before this tile's top barrier.
// vmcnt(8): 12 loads outstanding (tiles t,t+1,t+2 x 4/thread); in-order
// retirement => oldest 4 (tile t) landed; barrier makes it collective.
// XOR swizzle (chunk ^= row&3) folded into global source; ds_reads hit 64
// distinct 16B slots per wave => conflict-free.
// ---------------------------------------------------------------------------
template <int KT>
__device__ __forceinline__ void gemm256(const char* gA, const char* gB,
                                        char* sm, accfrag_t acc[8][4]) {
  const int tid = threadIdx.x;
  const int lane = tid & 63;
  const int w = tid >> 6, wm = w >> 2, wn = w & 3;
  const int LDB = KT * 64;  // row stride bytes (= K*2)
  const int ra = tid >> 2;
  const int swz = (((tid & 3) ^ (ra & 3)) << 4);
  const char* sA0 = gA + (size_t)ra * LDB + swz;
  const char* sB0 = gB + (size_t)ra * LDB + swz;
  const size_t half = (size_t)128 * LDB;
  const int dl = tid * 16;

  const int kswz = (((lane >> 4) ^ (lane & 3)) << 4);
  const int offAb = (wm * 128 + (lane & 15)) * 64 + kswz;
  const int offBb = (wn * 64 + (lane & 15)) * 64 + kswz;

  auto stageA = [&](int t3, char* buf) {
    const size_t ko = (size_t)t3 * 64;
    gload16(sA0 + ko, buf + dl);
    gload16(sA0 + half + ko, buf + 8192 + dl);
  };
  auto stageB = [&](int t3, char* buf) {
    const size_t ko = (size_t)t3 * 64;
    gload16(sB0 + ko, buf + 16384 + dl);
    gload16(sB0 + half + ko, buf + 24576 + dl);
  };

  // prologue: stage tiles 0,1,2
#pragma unroll
  for (int pt = 0; pt < 3; ++pt) {
    stageA(pt, sm + pt * 32768);
    stageB(pt, sm + pt * 32768);
  }

  for (int t = 0; t < KT; ++t) {
    asm volatile("s_waitcnt vmcnt(8)" ::: "memory");
    __builtin_amdgcn_s_barrier();
    asm volatile("" ::: "memory");
    const char* Ab = sm + (t & 3) * 32768;
    const char* Bb = Ab + 16384;
    char* stbuf = sm + ((t + 3) & 3) * 32768;
    const int t3 = (t + 3 < KT) ? (t + 3) : (KT - 1);

    // phase 0: stage next A, compute m-frags 0..3
    stageA(t3, stbuf);
    bfrag_t bf[4], af[4];
#pragma unroll
    for (int nf = 0; nf < 4; ++nf) bf[nf] = *(const bfrag_t*)(Bb + offBb + nf * 1024);
#pragma unroll
    for (int mf = 0; mf < 4; ++mf) af[mf] = *(const bfrag_t*)(Ab + offAb + mf * 1024);
    __builtin_amdgcn_s_setprio(1);
#pragma unroll
    for (int mf = 0; mf < 4; ++mf)
#pragma unroll
      for (int nf = 0; nf < 4; ++nf)
        acc[mf][nf] = MFMA16(af[mf], bf[nf], acc[mf][nf]);
    __builtin_amdgcn_s_setprio(0);

    // phase 1: stage next B, compute m-frags 4..7
    stageB(t3, stbuf);
#pragma unroll
    for (int mf = 0; mf < 4; ++mf) af[mf] = *(const bfrag_t*)(Ab + offAb + (4 + mf) * 1024);
    __builtin_amdgcn_s_setprio(1);
#pragma unroll
    for (int mf = 0; mf < 4; ++mf)
#pragma unroll
      for (int nf = 0; nf < 4; ++nf)
        acc[4 + mf][nf] = MFMA16(af[mf], bf[nf], acc[4 + mf][nf]);
    __builtin_amdgcn_s_setprio(0);
  }
  // drain: don't end the kernel with LDS writes in flight
  asm volatile("s_waitcnt vmcnt(0)" ::: "memory");
}

// ---------------------------------------------------------------------------
// GEMM1: h = GELU_tanh(x @ W1 + b1), bf16 out [JP][512][3072]
// ---------------------------------------------------------------------------
__global__ __launch_bounds__(512, 2)
void gemm1_k(const ushort_t* __restrict__ xb, const ushort_t* __restrict__ w1t,
             const float* __restrict__ e_b1, const float* __restrict__ g_b1,
             const int* __restrict__ tidx, ushort_t* __restrict__ h_out, int job0) {
  extern __shared__ char smdyn[];
  const int bx = blockIdx.x;  // 2 mt x 12 nt
  const int mt = bx & 1, nt = bx >> 1;
  const int jp = blockIdx.y, job = job0 + jp;
  const int b = job / 3, s = job - b * 3;
  const int e = (s < 2) ? tidx[b * 2 + s] : E_;
  const char* gA = (const char*)(xb + ((size_t)b * L_ + mt * 256) * D_);
  const char* gB = (const char*)(w1t + ((size_t)e * DFF_ + nt * 256) * D_);
  accfrag_t acc[8][4] = {};
  gemm256<24>(gA, gB, smdyn, acc);

  const float* b1 = (s < 2) ? (e_b1 + (size_t)e * DFF_) : g_b1;
  const int lane = threadIdx.x & 63, w = threadIdx.x >> 6;
  const int wm = w >> 2, wn = w & 3;
  const int row0 = mt * 256 + wm * 128 + ((lane >> 4) << 2);
  const int col0 = nt * 256 + wn * 64 + (lane & 15);
  ushort_t* hbase = h_out + (size_t)jp * L_ * DFF_;
#pragma unroll
  for (int mf = 0; mf < 8; ++mf)
#pragma unroll
    for (int nf = 0; nf < 4; ++nf) {
      const int col = col0 + nf * 16;
      const float bias = b1[col];
#pragma unroll
      for (int r = 0; r < 4; ++r) {
        const int row = row0 + mf * 16 + r;
        float v = acc[mf][nf][r] + bias;
        float u = 0.7978845608028654f * (v + 0.044715f * v * v * v);
        float th = 1.0f - 2.0f / (1.0f + __expf(2.0f * u));  // tanh(u)
        hbase[(size_t)row * DFF_ + col] = f2bf(0.5f * v * (1.0f + th));
      }
    }
}

// ---------------------------------------------------------------------------
// GEMM2: o = h @ W2 + b2 + x.  s<2 -> bf16 slot buffer; s==2 -> f32 d_out.
// ---------------------------------------------------------------------------
__global__ __launch_bounds__(512, 2)
void gemm2_k(const ushort_t* __restrict__ h_in, const ushort_t* __restrict__ w2t,
             const float* __restrict__ e_b2, const float* __restrict__ g_b2,
             const float* __restrict__ x_f, const int* __restrict__ tidx,
             ushort_t* __restrict__ slot_o, float* __restrict__ outp, int job0) {
  extern __shared__ char smdyn[];
  const int bx = blockIdx.x;  // 2 mt x 3 nt
  const int mt = bx & 1, nt = bx >> 1;
  const int jp = blockIdx.y, job = job0 + jp;
  const int b = job / 3, s = job - b * 3;
  const int e = (s < 2) ? tidx[b * 2 + s] : E_;
  const char* gA = (const char*)(h_in + ((size_t)jp * L_ + mt * 256) * DFF_);
  const char* gB = (const char*)(w2t + ((size_t)e * D_ + nt * 256) * DFF_);
  accfrag_t acc[8][4] = {};
  gemm256<96>(gA, gB, smdyn, acc);

  const float* b2 = (s < 2) ? (e_b2 + (size_t)e * D_) : g_b2;
  const int lane = threadIdx.x & 63, w = threadIdx.x >> 6;
  const int wm = w >> 2, wn = w & 3;
  const int row0 = mt * 256 + wm * 128 + ((lane >> 4) << 2);
  const int col0 = nt * 256 + wn * 64 + (lane & 15);
#pragma unroll
  for (int mf = 0; mf < 8; ++mf)
#pragma unroll
    for (int nf = 0; nf < 4; ++nf) {
      const int col = col0 + nf * 16;
      const float bias = b2[col];
#pragma unroll
      for (int r = 0; r < 4; ++r) {
        const int row = row0 + mf * 16 + r;
        float v = acc[mf][nf][r] + bias + x_f[((size_t)b * L_ + row) * D_ + col];
        if (s < 2)
          slot_o[(((size_t)b * 2 + s) * L_ + row) * D_ + col] = f2bf(v);
        else
          outp[((size_t)b * L_ + row) * D_ + col] = v;
      }
    }
}

// ---------------------------------------------------------------------------
// Weight transpose + f32->bf16: src [R][C] f32 (8 experts + general) -> [9][C][R] bf16
// ---------------------------------------------------------------------------
__global__ void transpose_cvt_k(const float* __restrict__ srcE, const float* __restrict__ srcG,
                                ushort_t* __restrict__ dst, int R, int C) {
  const int z = blockIdx.z;
  const float* src = (z < 8) ? (srcE + (size_t)z * R * C) : srcG;
  ushort_t* out = dst + (size_t)z * R * C;
  __shared__ float tile[32][33];
  const int c0 = blockIdx.x * 32, r0 = blockIdx.y * 32;
  const int tx = threadIdx.x & 31, ty = threadIdx.x >> 5;
#pragma unroll
  for (int i = 0; i < 32; i += 8)
    tile[ty + i][tx] = src[(size_t)(r0 + ty + i) * C + c0 + tx];
  __syncthreads();
#pragma unroll
  for (int i = 0; i < 32; i += 8)
    out[(size_t)(c0 + ty + i) * R + r0 + tx] = f2bf(tile[tx][ty + i]);
}

__global__ void cvt_x_k(const float* __restrict__ in, ushort_t* __restrict__ out) {
  const int i = (blockIdx.x * 256 + threadIdx.x) * 4;
  const float4 v = *(const float4*)(in + i);
  uint2 u;
  u.x = (uint32_t)f2bf(v.x) | ((uint32_t)f2bf(v.y) << 16);
  u.y = (uint32_t)f2bf(v.z) | ((uint32_t)f2bf(v.w) << 16);
  *(uint2*)(out + i) = u;
}

// ---------------------------------------------------------------------------
// Router: h = relu(emb @ We + cyc*Wc + b).  Partial: emb slice staged in LDS,
// one thread per output feature, 16 independent FMA chains (one per batch).
// ---------------------------------------------------------------------------
__global__ __launch_bounds__(256)
void router_partial_k(const float* __restrict__ emb, const float* __restrict__ We,
                      float* __restrict__ rp) {
  const int nt = blockIdx.x, kb = blockIdx.y;  // 12 x 16
  const int tid = threadIdx.x;
  __shared__ float semb[B_][256];
  const int k0 = kb * 256;
#pragma unroll
  for (int r = 0; r < B_; ++r) semb[r][tid] = emb[(size_t)r * DLLM_ + k0 + tid];
  __syncthreads();
  const int f = nt * 256 + tid;
  float acc[B_] = {};
  for (int k = 0; k < 256; ++k) {
    const float wv = We[(size_t)(k0 + k) * DFF_ + f];
#pragma unroll
    for (int j = 0; j < B_; ++j) acc[j] += semb[j][k] * wv;
  }
#pragma unroll
  for (int j = 0; j < B_; ++j)
    rp[((size_t)kb * B_ + j) * DFF_ + f] = acc[j];
}

__global__ void router_reduce_k(const float* __restrict__ rp, const float* __restrict__ cyc,
                                const float* __restrict__ Wc, const float* __restrict__ gb,
                                float* __restrict__ hr) {
  const int g = blockIdx.x * 256 + threadIdx.x;  // 0..49151
  const int b = g / DFF_, f = g - b * DFF_;
  float s = 0.0f;
#pragma unroll
  for (int kb = 0; kb < 16; ++kb)
    s += rp[((size_t)kb * B_ + b) * DFF_ + f];
  s += cyc[b] * Wc[f] + gb[f];
  hr[(size_t)b * DFF_ + f] = fmaxf(s, 0.0f);
}

__global__ void router_final_k(const float* __restrict__ hr, const float* __restrict__ Wo,
                               const float* __restrict__ bo, int* __restrict__ tidx,
                               float* __restrict__ gates) {
  const int b = blockIdx.x, tid = threadIdx.x;
  float acc[E_] = {};
  for (int f = tid; f < DFF_; f += 256) {
    const float hv = hr[(size_t)b * DFF_ + f];
#pragma unroll
    for (int o = 0; o < E_; ++o) acc[o] += hv * Wo[(size_t)f * E_ + o];
  }
  __shared__ float lred[E_][4];
#pragma unroll
  for (int o = 0; o < E_; ++o) {
    float v = acc[o];
#pragma unroll
    for (int off = 32; off > 0; off >>= 1) v += __shfl_down(v, off, 64);
    if ((tid & 63) == 0) lred[o][tid >> 6] = v;
  }
  __syncthreads();
  if (tid == 0) {
    float lg[E_];
    float mx = -1e30f;
    for (int o = 0; o < E_; ++o) {
      lg[o] = lred[o][0] + lred[o][1] + lred[o][2] + lred[o][3] + bo[o];
      mx = fmaxf(mx, lg[o]);
    }
    int i1 = 0;
    for (int o = 1; o < E_; ++o) if (lg[o] > lg[i1]) i1 = o;
    int i2 = (i1 == 0) ? 1 : 0;
    for (int o = 0; o < E_; ++o) if (o != i1 && lg[o] > lg[i2]) i2 = o;
    float p[E_], sum = 0.0f;
    for (int o = 0; o < E_; ++o) { p[o] = __expf(lg[o] - mx); sum += p[o]; }
    const float p1 = p[i1] / sum, p2 = p[i2] / sum;
    const float den = p1 + p2 + 1e-9f;
    tidx[b * 2] = i1; tidx[b * 2 + 1] = i2;
    gates[b * 2] = p1 / den; gates[b * 2 + 1] = p2 / den;
  }
}

// ---------------------------------------------------------------------------
// Final: 3-way LayerNorm + gating + bf16 cast of combined; f32 output.
// ---------------------------------------------------------------------------
__global__ __launch_bounds__(256)
void final_ln_k(float* __restrict__ outp, const ushort_t* __restrict__ so,
                const float* __restrict__ gates, const int* __restrict__ tidx,
                const float* __restrict__ e_gam, const float* __restrict__ e_bet,
                const float* __restrict__ g_gam, const float* __restrict__ g_bet) {
  const int row = blockIdx.x;
  const int b = row >> 9, l = row & 511;
  const int tid = threadIdx.x;
  __shared__ float red4[4];
  float* gr = outp + (size_t)row * D_;
  const ushort_t* s0 = so + (((size_t)b * 2 + 0) * L_ + l) * D_;
  const ushort_t* s1 = so + (((size_t)b * 2 + 1) * L_ + l) * D_;
  float a0[3], a1[3], a2[3];
#pragma unroll
  for (int j = 0; j < 3; ++j) {
    const int d = tid + j * 256;
    a0[j] = gr[d];
    a1[j] = bf2f(s0[d]);
    a2[j] = bf2f(s1[d]);
  }
  auto bsum = [&](float v) -> float {
#pragma unroll
    for (int o = 32; o > 0; o >>= 1) v += __shfl_down(v, o, 64);
    if ((tid & 63) == 0) red4[tid >> 6] = v;
    __syncthreads();
    const float r = red4[0] + red4[1] + red4[2] + red4[3];
    __syncthreads();
    return r;
  };
  const float sg = bsum(a0[0] + a0[1] + a0[2]);
  const float qg = bsum(a0[0] * a0[0] + a0[1] * a0[1] + a0[2] * a0[2]);
  const float s0s = bsum(a1[0] + a1[1] + a1[2]);
  const float q0s = bsum(a1[0] * a1[0] + a1[1] * a1[1] + a1[2] * a1[2]);
  const float s1s = bsum(a2[0] + a2[1] + a2[2]);
  const float q1s = bsum(a2[0] * a2[0] + a2[1] * a2[1] + a2[2] * a2[2]);
  const float inv = 1.0f / 768.0f;
  const float mug = sg * inv, rg = rsqrtf(qg * inv - mug * mug + 1e-5f);
  const float mu0 = s0s * inv, r0 = rsqrtf(q0s * inv - mu0 * mu0 + 1e-5f);
  const float mu1 = s1s * inv, r1 = rsqrtf(q1s * inv - mu1 * mu1 + 1e-5f);
  const int e0 = tidx[b * 2], e1 = tidx[b * 2 + 1];
  const float g0 = gates[b * 2], g1 = gates[b * 2 + 1];
#pragma unroll
  for (int j = 0; j < 3; ++j) {
    const int d = tid + j * 256;
    const float lng = (a0[j] - mug) * rg * g_gam[d] + g_bet[d];
    const float ln0 = (a1[j] - mu0) * r0 * e_gam[(size_t)e0 * D_ + d] + e_bet[(size_t)e0 * D_ + d];
    const float ln1 = (a2[j] - mu1) * r1 * e_gam[(size_t)e1 * D_ + d] + e_bet[(size_t)e1 * D_ + d];
    const float comb = g0 * ln0 + g1 * ln1;
    gr[d] = lng + bf2f(f2bf(comb));
  }
}

// ---------------------------------------------------------------------------
extern "C" void kernel_launch(void* const* d_in, const int* in_sizes, int n_in,
                              void* d_out, int out_size, void* d_ws, size_t ws_size,
                              hipStream_t stream) {
  const float* x_f  = (const float*)d_in[0];
  const float* cyc  = (const float*)d_in[1];
  const float* emb  = (const float*)d_in[2];
  const float* We   = (const float*)d_in[3];
  const float* Wc   = (const float*)d_in[4];
  const float* gb   = (const float*)d_in[5];
  const float* Wo   = (const float*)d_in[6];
  const float* bo   = (const float*)d_in[7];
  const float* e_w1 = (const float*)d_in[8];
  const float* e_b1 = (const float*)d_in[9];
  const float* e_w2 = (const float*)d_in[10];
  const float* e_b2 = (const float*)d_in[11];
  const float* e_gam = (const float*)d_in[12];
  const float* e_bet = (const float*)d_in[13];
  const float* g_w1 = (const float*)d_in[14];
  const float* g_b1 = (const float*)d_in[15];
  const float* g_w2 = (const float*)d_in[16];
  const float* g_b2 = (const float*)d_in[17];
  const float* g_gam = (const float*)d_in[18];
  const float* g_bet = (const float*)d_in[19];
  float* outp = (float*)d_out;
  char* ws = (char*)d_ws;

  size_t off = 0;
  auto alloc = [&](size_t bytes) { size_t o = off; off = (off + bytes + 255) & ~(size_t)255; return o; };
  const size_t o_idx  = alloc(32 * 4);
  const size_t o_gate = alloc(32 * 4);
  const size_t o_hr   = alloc((size_t)B_ * DFF_ * 4);
  const size_t o_rp   = alloc((size_t)16 * B_ * DFF_ * 4);
  const size_t o_xb   = alloc((size_t)B_ * L_ * D_ * 2);
  const size_t o_w1t  = alloc((size_t)9 * DFF_ * D_ * 2);
  const size_t o_w2t  = alloc((size_t)9 * D_ * DFF_ * 2);
  const size_t o_so   = alloc((size_t)B_ * 2 * L_ * D_ * 2);
  const size_t o_h    = off;

  int JP = 1;
  const int divs[10] = {48, 24, 16, 12, 8, 6, 4, 3, 2, 1};
  for (int k = 0; k < 10; ++k) {
    if (o_h + (size_t)divs[k] * L_ * DFF_ * 2 <= ws_size) { JP = divs[k]; break; }
  }

  ushort_t* xb    = (ushort_t*)(ws + o_xb);
  ushort_t* w1t   = (ushort_t*)(ws + o_w1t);
  ushort_t* w2t   = (ushort_t*)(ws + o_w2t);
  ushort_t* so    = (ushort_t*)(ws + o_so);
  ushort_t* h_ws  = (ushort_t*)(ws + o_h);
  int*      tidx  = (int*)(ws + o_idx);
  float*    gates = (float*)(ws + o_gate);
  float*    hr    = (float*)(ws + o_hr);
  float*    rp    = (float*)(ws + o_rp);

  hipFuncSetAttribute((const void*)gemm1_k, hipFuncAttributeMaxDynamicSharedMemorySize, 131072);
  hipFuncSetAttribute((const void*)gemm2_k, hipFuncAttributeMaxDynamicSharedMemorySize, 131072);

  cvt_x_k<<<dim3((B_ * L_ * D_) / 1024), dim3(256), 0, stream>>>(x_f, xb);
  transpose_cvt_k<<<dim3(96, 24, 9), dim3(256), 0, stream>>>(e_w1, g_w1, w1t, D_, DFF_);
  transpose_cvt_k<<<dim3(24, 96, 9), dim3(256), 0, stream>>>(e_w2, g_w2, w2t, DFF_, D_);
  router_partial_k<<<dim3(12, 16), dim3(256), 0, stream>>>(emb, We, rp);
  router_reduce_k<<<dim3(192), dim3(256), 0, stream>>>(rp, cyc, Wc, gb, hr);
  router_final_k<<<dim3(16), dim3(256), 0, stream>>>(hr, Wo, bo, tidx, gates);

  const int passes = 48 / JP;
  for (int p = 0; p < passes; ++p) {
    gemm1_k<<<dim3(24, JP), dim3(512), 131072, stream>>>(xb, w1t, e_b1, g_b1, tidx, h_ws, p * JP);
    gemm2_k<<<dim3(6, JP), dim3(512), 131072, stream>>>(h_ws, w2t, e_b2, g_b2, x_f, tidx, so, outp, p * JP);
  }
  final_ln_k<<<dim3(B_ * L_), dim3(256), 0, stream>>>(outp, so, gates, tidx,
                                                      e_gam, e_bet, g_gam, g_bet);
}

// Round 3
// 480.865 us; speedup vs baseline: 1.3232x; 1.2331x over previous
//
#include <hip/hip_runtime.h>
#include <cstdint>

#define B_    16
#define L_    512
#define D_    768
#define DFF_  3072
#define DLLM_ 4096
#define E_    8

typedef unsigned short ushort_t;
typedef __attribute__((ext_vector_type(4))) float accfrag_t;
typedef __attribute__((ext_vector_type(8))) short bfrag_t;

typedef __attribute__((address_space(3))) uint32_t lds_u32;
typedef __attribute__((address_space(1))) uint32_t glb_u32;

__device__ inline void gload16(const void* g, void* l) {
  __builtin_amdgcn_global_load_lds((const glb_u32*)(uintptr_t)g,
                                   (lds_u32*)(uint32_t)(uintptr_t)l, 16, 0, 0);
}

__device__ inline ushort_t f2bf(float f) {
  uint32_t u = __float_as_uint(f);
  return (ushort_t)((u + 0x7FFFu + ((u >> 16) & 1u)) >> 16);  // RNE
}
__device__ inline float bf2f(ushort_t v) { return __uint_as_float(((uint32_t)v) << 16); }

#define MFMA16(a, b, c) __builtin_amdgcn_mfma_f32_16x16x32_bf16(a, b, c, 0, 0, 0)

// ---------------------------------------------------------------------------
// 256(M) x 384(N) tile GEMM, BK=32, 8 waves (2M x 4N), wave tile 128x96.
// 3-deep LDS buffering (3 x 40KB = 120KB), counted vmcnt(5), raw s_barrier,
// setprio around MFMA clusters.
// Swizzle: LDS 16B-chunk index = global_chunk ^ ((row>>1)&3).  Bank group of a
// 16B slot is (row&1)*4 + chunk; XOR with row bits 2:1 makes every 16-lane
// phase of a frag-read hit each bank group exactly twice (2-way = free).
// Swizzle is folded into the per-lane GLOBAL source address (LDS dest of
// global_load_lds must stay linear) and into the ds_read byte offset.
// Per tile, per thread: 2 A-loads + 3 B-loads = 5 gload16.  At top of iter t
// outstanding = {t:5, t+1:5}; vmcnt(5) proves tile t landed (in-order retire).
// Buffer (t+2)%3 == (t-1)%3, whose readers finished before iter-t's barrier.
// ---------------------------------------------------------------------------
template <int KT>
__device__ __forceinline__ void gemm_body(const char* gA, const char* gB,
                                          char* sm, accfrag_t acc[8][6]) {
  const int tid = threadIdx.x;
  const int lane = tid & 63;
  const int w = tid >> 6, wm = w >> 2, wn = w & 3;
  const int LDB = KT * 64;  // row stride in bytes (= K*2)
  const int ra = tid >> 2;
  const int swz = (((tid & 3) ^ ((ra >> 1) & 3)) << 4);
  const char* sA0 = gA + (size_t)ra * LDB + swz;
  const char* sB0 = gB + (size_t)ra * LDB + swz;
  const int dl = tid * 16;

  const int kswz = (((lane >> 4) ^ ((lane >> 1) & 3)) << 4);
  const int offA = (wm * 128 + (lane & 15)) * 64 + kswz;
  const int offB = 16384 + (wn * 96 + (lane & 15)) * 64 + kswz;

  auto stageA = [&](int t, char* buf) {
    const size_t ko = (size_t)t * 64;
#pragma unroll
    for (int j = 0; j < 2; ++j)
      gload16(sA0 + (size_t)j * 128 * LDB + ko, buf + j * 8192 + dl);
  };
  auto stageB = [&](int t, char* buf) {
    const size_t ko = (size_t)t * 64;
#pragma unroll
    for (int j = 0; j < 3; ++j)
      gload16(sB0 + (size_t)j * 128 * LDB + ko, buf + 16384 + j * 8192 + dl);
  };

  // prologue: stage tiles 0,1 (order matters for vmcnt accounting)
  stageA(0, sm);
  stageB(0, sm);
  stageA(1, sm + 40960);
  stageB(1, sm + 40960);

  int c0 = 0, c2 = 2;  // buffer of tile t, buffer of tile t+2
  for (int t = 0; t < KT; ++t) {
    asm volatile("s_waitcnt vmcnt(5)" ::: "memory");
    __builtin_amdgcn_s_barrier();
    asm volatile("" ::: "memory");
    const char* bb = sm + c0 * 40960;
    char* stbuf = sm + c2 * 40960;
    const int t2 = (t + 2 < KT) ? (t + 2) : (KT - 1);

    // phase 0: stage next A, compute m-frags 0..3
    stageA(t2, stbuf);
    bfrag_t bf[6], af[4];
#pragma unroll
    for (int nf = 0; nf < 6; ++nf) bf[nf] = *(const bfrag_t*)(bb + offB + nf * 1024);
#pragma unroll
    for (int mf = 0; mf < 4; ++mf) af[mf] = *(const bfrag_t*)(bb + offA + mf * 1024);
    __builtin_amdgcn_s_setprio(1);
#pragma unroll
    for (int mf = 0; mf < 4; ++mf)
#pragma unroll
      for (int nf = 0; nf < 6; ++nf)
        acc[mf][nf] = MFMA16(af[mf], bf[nf], acc[mf][nf]);
    __builtin_amdgcn_s_setprio(0);

    // phase 1: stage next B, compute m-frags 4..7
    stageB(t2, stbuf);
#pragma unroll
    for (int mf = 0; mf < 4; ++mf) af[mf] = *(const bfrag_t*)(bb + offA + (4 + mf) * 1024);
    __builtin_amdgcn_s_setprio(1);
#pragma unroll
    for (int mf = 0; mf < 4; ++mf)
#pragma unroll
      for (int nf = 0; nf < 6; ++nf)
        acc[4 + mf][nf] = MFMA16(af[mf], bf[nf], acc[4 + mf][nf]);
    __builtin_amdgcn_s_setprio(0);

    c0 = (c0 == 2) ? 0 : c0 + 1;
    c2 = (c2 == 2) ? 0 : c2 + 1;
  }
  asm volatile("s_waitcnt vmcnt(0)" ::: "memory");
}

// ---------------------------------------------------------------------------
// GEMM1: h = GELU_tanh(x @ W1 + b1), bf16 out [JP][512][3072]
// grid: (2 mt x 8 nt, JP) = 768 blocks at JP=48 -> exactly 3 waves of 256 CUs
// ---------------------------------------------------------------------------
__global__ __launch_bounds__(512, 2)
void gemm1_k(const ushort_t* __restrict__ xb, const ushort_t* __restrict__ w1t,
             const float* __restrict__ e_b1, const float* __restrict__ g_b1,
             const int* __restrict__ tidx, ushort_t* __restrict__ h_out, int job0) {
  extern __shared__ char smdyn[];
  const int bx = blockIdx.x;
  const int mt = bx & 1, nt = bx >> 1;  // nt 0..7
  const int jp = blockIdx.y, job = job0 + jp;
  const int b = job / 3, s = job - b * 3;
  const int e = (s < 2) ? tidx[b * 2 + s] : E_;
  const char* gA = (const char*)(xb + ((size_t)b * L_ + mt * 256) * D_);
  const char* gB = (const char*)(w1t + ((size_t)e * DFF_ + nt * 384) * D_);
  accfrag_t acc[8][6] = {};
  gemm_body<24>(gA, gB, smdyn, acc);

  const float* b1 = (s < 2) ? (e_b1 + (size_t)e * DFF_) : g_b1;
  const int lane = threadIdx.x & 63, w = threadIdx.x >> 6;
  const int wm = w >> 2, wn = w & 3;
  const int row0 = mt * 256 + wm * 128 + ((lane >> 4) << 2);
  const int col0 = nt * 384 + wn * 96 + (lane & 15);
  ushort_t* hbase = h_out + (size_t)jp * L_ * DFF_;
#pragma unroll
  for (int mf = 0; mf < 8; ++mf)
#pragma unroll
    for (int nf = 0; nf < 6; ++nf) {
      const int col = col0 + nf * 16;
      const float bias = b1[col];
#pragma unroll
      for (int r = 0; r < 4; ++r) {
        const int row = row0 + mf * 16 + r;
        float v = acc[mf][nf][r] + bias;
        float u = 0.7978845608028654f * (v + 0.044715f * v * v * v);
        float th = 1.0f - 2.0f / (1.0f + __expf(2.0f * u));  // tanh(u)
        hbase[(size_t)row * DFF_ + col] = f2bf(0.5f * v * (1.0f + th));
      }
    }
}

// ---------------------------------------------------------------------------
// GEMM2: o = h @ W2 + b2 + x.  s<2 -> bf16 slot buffer; s==2 -> f32 d_out.
// grid: (2 mt x 2 nt, JP) = 192 blocks at JP=48 -> single wave of CUs
// ---------------------------------------------------------------------------
__global__ __launch_bounds__(512, 2)
void gemm2_k(const ushort_t* __restrict__ h_in, const ushort_t* __restrict__ w2t,
             const float* __restrict__ e_b2, const float* __restrict__ g_b2,
             const float* __restrict__ x_f, const int* __restrict__ tidx,
             ushort_t* __restrict__ slot_o, float* __restrict__ outp, int job0) {
  extern __shared__ char smdyn[];
  const int bx = blockIdx.x;
  const int mt = bx & 1, nt = bx >> 1;  // nt 0..1
  const int jp = blockIdx.y, job = job0 + jp;
  const int b = job / 3, s = job - b * 3;
  const int e = (s < 2) ? tidx[b * 2 + s] : E_;
  const char* gA = (const char*)(h_in + ((size_t)jp * L_ + mt * 256) * DFF_);
  const char* gB = (const char*)(w2t + ((size_t)e * D_ + nt * 384) * DFF_);
  accfrag_t acc[8][6] = {};
  gemm_body<96>(gA, gB, smdyn, acc);

  const float* b2 = (s < 2) ? (e_b2 + (size_t)e * D_) : g_b2;
  const int lane = threadIdx.x & 63, w = threadIdx.x >> 6;
  const int wm = w >> 2, wn = w & 3;
  const int row0 = mt * 256 + wm * 128 + ((lane >> 4) << 2);
  const int col0 = nt * 384 + wn * 96 + (lane & 15);
#pragma unroll
  for (int mf = 0; mf < 8; ++mf)
#pragma unroll
    for (int nf = 0; nf < 6; ++nf) {
      const int col = col0 + nf * 16;
      const float bias = b2[col];
#pragma unroll
      for (int r = 0; r < 4; ++r) {
        const int row = row0 + mf * 16 + r;
        float v = acc[mf][nf][r] + bias + x_f[((size_t)b * L_ + row) * D_ + col];
        if (s < 2)
          slot_o[(((size_t)b * 2 + s) * L_ + row) * D_ + col] = f2bf(v);
        else
          outp[((size_t)b * L_ + row) * D_ + col] = v;
      }
    }
}

// ---------------------------------------------------------------------------
// Weight transpose + f32->bf16: src [R][C] f32 (8 experts + general) -> [9][C][R] bf16
// ---------------------------------------------------------------------------
__global__ void transpose_cvt_k(const float* __restrict__ srcE, const float* __restrict__ srcG,
                                ushort_t* __restrict__ dst, int R, int C) {
  const int z = blockIdx.z;
  const float* src = (z < 8) ? (srcE + (size_t)z * R * C) : srcG;
  ushort_t* out = dst + (size_t)z * R * C;
  __shared__ float tile[32][33];
  const int c0 = blockIdx.x * 32, r0 = blockIdx.y * 32;
  const int tx = threadIdx.x & 31, ty = threadIdx.x >> 5;
#pragma unroll
  for (int i = 0; i < 32; i += 8)
    tile[ty + i][tx] = src[(size_t)(r0 + ty + i) * C + c0 + tx];
  __syncthreads();
#pragma unroll
  for (int i = 0; i < 32; i += 8)
    out[(size_t)(c0 + ty + i) * R + r0 + tx] = f2bf(tile[tx][ty + i]);
}

__global__ void cvt_x_k(const float* __restrict__ in, ushort_t* __restrict__ out) {
  const int i = (blockIdx.x * 256 + threadIdx.x) * 4;
  const float4 v = *(const float4*)(in + i);
  uint2 u;
  u.x = (uint32_t)f2bf(v.x) | ((uint32_t)f2bf(v.y) << 16);
  u.y = (uint32_t)f2bf(v.z) | ((uint32_t)f2bf(v.w) << 16);
  *(uint2*)(out + i) = u;
}

// ---------------------------------------------------------------------------
// Router: h = relu(emb @ We + cyc*Wc + b)
// ---------------------------------------------------------------------------
__global__ __launch_bounds__(256)
void router_partial_k(const float* __restrict__ emb, const float* __restrict__ We,
                      float* __restrict__ rp) {
  const int nt = blockIdx.x, kb = blockIdx.y;  // 12 x 16
  const int tid = threadIdx.x;
  __shared__ float semb[B_][256];
  const int k0 = kb * 256;
#pragma unroll
  for (int r = 0; r < B_; ++r) semb[r][tid] = emb[(size_t)r * DLLM_ + k0 + tid];
  __syncthreads();
  const int f = nt * 256 + tid;
  float acc[B_] = {};
  for (int k = 0; k < 256; ++k) {
    const float wv = We[(size_t)(k0 + k) * DFF_ + f];
#pragma unroll
    for (int j = 0; j < B_; ++j) acc[j] += semb[j][k] * wv;
  }
#pragma unroll
  for (int j = 0; j < B_; ++j)
    rp[((size_t)kb * B_ + j) * DFF_ + f] = acc[j];
}

__global__ void router_reduce_k(const float* __restrict__ rp, const float* __restrict__ cyc,
                                const float* __restrict__ Wc, const float* __restrict__ gb,
                                float* __restrict__ hr) {
  const int g = blockIdx.x * 256 + threadIdx.x;
  const int b = g / DFF_, f = g - b * DFF_;
  float s = 0.0f;
#pragma unroll
  for (int kb = 0; kb < 16; ++kb)
    s += rp[((size_t)kb * B_ + b) * DFF_ + f];
  s += cyc[b] * Wc[f] + gb[f];
  hr[(size_t)b * DFF_ + f] = fmaxf(s, 0.0f);
}

__global__ void router_final_k(const float* __restrict__ hr, const float* __restrict__ Wo,
                               const float* __restrict__ bo, int* __restrict__ tidx,
                               float* __restrict__ gates) {
  const int b = blockIdx.x, tid = threadIdx.x;
  float acc[E_] = {};
  for (int f = tid; f < DFF_; f += 256) {
    const float hv = hr[(size_t)b * DFF_ + f];
#pragma unroll
    for (int o = 0; o < E_; ++o) acc[o] += hv * Wo[(size_t)f * E_ + o];
  }
  __shared__ float lred[E_][4];
#pragma unroll
  for (int o = 0; o < E_; ++o) {
    float v = acc[o];
#pragma unroll
    for (int off = 32; off > 0; off >>= 1) v += __shfl_down(v, off, 64);
    if ((tid & 63) == 0) lred[o][tid >> 6] = v;
  }
  __syncthreads();
  if (tid == 0) {
    float lg[E_];
    float mx = -1e30f;
    for (int o = 0; o < E_; ++o) {
      lg[o] = lred[o][0] + lred[o][1] + lred[o][2] + lred[o][3] + bo[o];
      mx = fmaxf(mx, lg[o]);
    }
    int i1 = 0;
    for (int o = 1; o < E_; ++o) if (lg[o] > lg[i1]) i1 = o;
    int i2 = (i1 == 0) ? 1 : 0;
    for (int o = 0; o < E_; ++o) if (o != i1 && lg[o] > lg[i2]) i2 = o;
    float p[E_], sum = 0.0f;
    for (int o = 0; o < E_; ++o) { p[o] = __expf(lg[o] - mx); sum += p[o]; }
    const float p1 = p[i1] / sum, p2 = p[i2] / sum;
    const float den = p1 + p2 + 1e-9f;
    tidx[b * 2] = i1; tidx[b * 2 + 1] = i2;
    gates[b * 2] = p1 / den; gates[b * 2 + 1] = p2 / den;
  }
}

// ---------------------------------------------------------------------------
// Final: 3-way LayerNorm + gating + bf16 cast of combined; f32 output.
// ---------------------------------------------------------------------------
__global__ __launch_bounds__(256)
void final_ln_k(float* __restrict__ outp, const ushort_t* __restrict__ so,
                const float* __restrict__ gates, const int* __restrict__ tidx,
                const float* __restrict__ e_gam, const float* __restrict__ e_bet,
                const float* __restrict__ g_gam, const float* __restrict__ g_bet) {
  const int row = blockIdx.x;
  const int b = row >> 9, l = row & 511;
  const int tid = threadIdx.x;
  __shared__ float red4[4];
  float* gr = outp + (size_t)row * D_;
  const ushort_t* s0 = so + (((size_t)b * 2 + 0) * L_ + l) * D_;
  const ushort_t* s1 = so + (((size_t)b * 2 + 1) * L_ + l) * D_;
  float a0[3], a1[3], a2[3];
#pragma unroll
  for (int j = 0; j < 3; ++j) {
    const int d = tid + j * 256;
    a0[j] = gr[d];
    a1[j] = bf2f(s0[d]);
    a2[j] = bf2f(s1[d]);
  }
  auto bsum = [&](float v) -> float {
#pragma unroll
    for (int o = 32; o > 0; o >>= 1) v += __shfl_down(v, o, 64);
    if ((tid & 63) == 0) red4[tid >> 6] = v;
    __syncthreads();
    const float r = red4[0] + red4[1] + red4[2] + red4[3];
    __syncthreads();
    return r;
  };
  const float sg = bsum(a0[0] + a0[1] + a0[2]);
  const float qg = bsum(a0[0] * a0[0] + a0[1] * a0[1] + a0[2] * a0[2]);
  const float s0s = bsum(a1[0] + a1[1] + a1[2]);
  const float q0s = bsum(a1[0] * a1[0] + a1[1] * a1[1] + a1[2] * a1[2]);
  const float s1s = bsum(a2[0] + a2[1] + a2[2]);
  const float q1s = bsum(a2[0] * a2[0] + a2[1] * a2[1] + a2[2] * a2[2]);
  const float inv = 1.0f / 768.0f;
  const float mug = sg * inv, rg = rsqrtf(qg * inv - mug * mug + 1e-5f);
  const float mu0 = s0s * inv, r0 = rsqrtf(q0s * inv - mu0 * mu0 + 1e-5f);
  const float mu1 = s1s * inv, r1 = rsqrtf(q1s * inv - mu1 * mu1 + 1e-5f);
  const int e0 = tidx[b * 2], e1 = tidx[b * 2 + 1];
  const float g0 = gates[b * 2], g1 = gates[b * 2 + 1];
#pragma unroll
  for (int j = 0; j < 3; ++j) {
    const int d = tid + j * 256;
    const float lng = (a0[j] - mug) * rg * g_gam[d] + g_bet[d];
    const float ln0 = (a1[j] - mu0) * r0 * e_gam[(size_t)e0 * D_ + d] + e_bet[(size_t)e0 * D_ + d];
    const float ln1 = (a2[j] - mu1) * r1 * e_gam[(size_t)e1 * D_ + d] + e_bet[(size_t)e1 * D_ + d];
    const float comb = g0 * ln0 + g1 * ln1;
    gr[d] = lng + bf2f(f2bf(comb));
  }
}

// ---------------------------------------------------------------------------
extern "C" void kernel_launch(void* const* d_in, const int* in_sizes, int n_in,
                              void* d_out, int out_size, void* d_ws, size_t ws_size,
                              hipStream_t stream) {
  const float* x_f  = (const float*)d_in[0];
  const float* cyc  = (const float*)d_in[1];
  const float* emb  = (const float*)d_in[2];
  const float* We   = (const float*)d_in[3];
  const float* Wc   = (const float*)d_in[4];
  const float* gb   = (const float*)d_in[5];
  const float* Wo   = (const float*)d_in[6];
  const float* bo   = (const float*)d_in[7];
  const float* e_w1 = (const float*)d_in[8];
  const float* e_b1 = (const float*)d_in[9];
  const float* e_w2 = (const float*)d_in[10];
  const float* e_b2 = (const float*)d_in[11];
  const float* e_gam = (const float*)d_in[12];
  const float* e_bet = (const float*)d_in[13];
  const float* g_w1 = (const float*)d_in[14];
  const float* g_b1 = (const float*)d_in[15];
  const float* g_w2 = (const float*)d_in[16];
  const float* g_b2 = (const float*)d_in[17];
  const float* g_gam = (const float*)d_in[18];
  const float* g_bet = (const float*)d_in[19];
  float* outp = (float*)d_out;
  char* ws = (char*)d_ws;

  size_t off = 0;
  auto alloc = [&](size_t bytes) { size_t o = off; off = (off + bytes + 255) & ~(size_t)255; return o; };
  const size_t o_idx  = alloc(32 * 4);
  const size_t o_gate = alloc(32 * 4);
  const size_t o_hr   = alloc((size_t)B_ * DFF_ * 4);
  const size_t o_rp   = alloc((size_t)16 * B_ * DFF_ * 4);
  const size_t o_xb   = alloc((size_t)B_ * L_ * D_ * 2);
  const size_t o_w1t  = alloc((size_t)9 * DFF_ * D_ * 2);
  const size_t o_w2t  = alloc((size_t)9 * D_ * DFF_ * 2);
  const size_t o_so   = alloc((size_t)B_ * 2 * L_ * D_ * 2);
  const size_t o_h    = off;

  int JP = 1;
  const int divs[10] = {48, 24, 16, 12, 8, 6, 4, 3, 2, 1};
  for (int k = 0; k < 10; ++k) {
    if (o_h + (size_t)divs[k] * L_ * DFF_ * 2 <= ws_size) { JP = divs[k]; break; }
  }

  ushort_t* xb    = (ushort_t*)(ws + o_xb);
  ushort_t* w1t   = (ushort_t*)(ws + o_w1t);
  ushort_t* w2t   = (ushort_t*)(ws + o_w2t);
  ushort_t* so    = (ushort_t*)(ws + o_so);
  ushort_t* h_ws  = (ushort_t*)(ws + o_h);
  int*      tidx  = (int*)(ws + o_idx);
  float*    gates = (float*)(ws + o_gate);
  float*    hr    = (float*)(ws + o_hr);
  float*    rp    = (float*)(ws + o_rp);

  hipFuncSetAttribute((const void*)gemm1_k, hipFuncAttributeMaxDynamicSharedMemorySize, 122880);
  hipFuncSetAttribute((const void*)gemm2_k, hipFuncAttributeMaxDynamicSharedMemorySize, 122880);

  cvt_x_k<<<dim3((B_ * L_ * D_) / 1024), dim3(256), 0, stream>>>(x_f, xb);
  transpose_cvt_k<<<dim3(96, 24, 9), dim3(256), 0, stream>>>(e_w1, g_w1, w1t, D_, DFF_);
  transpose_cvt_k<<<dim3(24, 96, 9), dim3(256), 0, stream>>>(e_w2, g_w2, w2t, DFF_, D_);
  router_partial_k<<<dim3(12, 16), dim3(256), 0, stream>>>(emb, We, rp);
  router_reduce_k<<<dim3(192), dim3(256), 0, stream>>>(rp, cyc, Wc, gb, hr);
  router_final_k<<<dim3(16), dim3(256), 0, stream>>>(hr, Wo, bo, tidx, gates);

  const int passes = 48 / JP;
  for (int p = 0; p < passes; ++p) {
    gemm1_k<<<dim3(16, JP), dim3(512), 122880, stream>>>(xb, w1t, e_b1, g_b1, tidx, h_ws, p * JP);
    gemm2_k<<<dim3(4, JP), dim3(512), 122880, stream>>>(h_ws, w2t, e_b2, g_b2, x_f, tidx, so, outp, p * JP);
  }
  final_ln_k<<<dim3(B_ * L_), dim3(256), 0, stream>>>(outp, so, gates, tidx,
                                                      e_gam, e_bet, g_gam, g_bet);
}